// Round 3
// baseline (421.018 us; speedup 1.0000x reference)
//
#include <hip/hip_runtime.h>
#include <hip/hip_bf16.h>
#include <math.h>

#define NUM_USERS  100000
#define NUM_ITEMS  50000
#define N_NODES    150000
#define EMBED_DIM  64
#define NUM_EDGES  1250000
#define MLP_HID    32
#define SCAN_B     1024
#define SCAN_NB    ((N_NODES + SCAN_B - 1) / SCAN_B)   // 147
#define NPW        4   // nodes per wave in propagate kernels
#define PAD(x)     (((x) + 15) & ~15)                  // segment pad to 16

// ---------------------------------------------------------------------------
// Kernel 1: histogram of cols + within-bucket rank (atomic return value IS
// the rank -> downstream scatter needs no atomics).
// ---------------------------------------------------------------------------
__global__ void hist_rank(const int* __restrict__ edge_index,
                          int* __restrict__ cnt,
                          int* __restrict__ rank) {
    int e = blockIdx.x * blockDim.x + threadIdx.x;
    if (e >= NUM_EDGES) return;
    int c = edge_index[NUM_EDGES + e];
    rank[e] = atomicAdd(&cnt[c], 1);
}

// ---------------------------------------------------------------------------
// Device-wide exclusive scan of PADDED cnt -> row_ptr, 3 phases.
// Every segment is a multiple of 16 -> guard-free propagate inner loop.
// ---------------------------------------------------------------------------
__global__ void scan_partial(const int* __restrict__ cnt,
                             int* __restrict__ part) {
    __shared__ int s[SCAN_B];
    int tid = threadIdx.x;
    int i = blockIdx.x * SCAN_B + tid;
    s[tid] = (i < N_NODES) ? PAD(cnt[i]) : 0;
    __syncthreads();
#pragma unroll
    for (int off = SCAN_B / 2; off > 0; off >>= 1) {
        if (tid < off) s[tid] += s[tid + off];
        __syncthreads();
    }
    if (tid == 0) part[blockIdx.x] = s[0];
}

__global__ void scan_offsets(const int* __restrict__ part,
                             int* __restrict__ base_off) {
    __shared__ int s[256];
    int tid = threadIdx.x;
    int v = (tid < SCAN_NB) ? part[tid] : 0;
    s[tid] = v;
    __syncthreads();
#pragma unroll
    for (int off = 1; off < 256; off <<= 1) {
        int t = (tid >= off) ? s[tid - off] : 0;
        __syncthreads();
        s[tid] += t;
        __syncthreads();
    }
    if (tid < SCAN_NB) base_off[tid] = s[tid] - v;   // exclusive
}

__global__ void scan_apply(const int* __restrict__ cnt,
                           const int* __restrict__ base_off,
                           int* __restrict__ row_ptr) {
    __shared__ int s[SCAN_B];
    int tid = threadIdx.x;
    int i = blockIdx.x * SCAN_B + tid;
    int v = (i < N_NODES) ? PAD(cnt[i]) : 0;
    s[tid] = v;
    __syncthreads();
    for (int off = 1; off < SCAN_B; off <<= 1) {
        int t = (tid >= off) ? s[tid - off] : 0;
        __syncthreads();
        s[tid] += t;
        __syncthreads();
    }
    if (i < N_NODES) row_ptr[i] = s[tid] - v + base_off[blockIdx.x];
    if (i == N_NODES - 1) row_ptr[N_NODES] = s[tid] + base_off[blockIdx.x];
}

// ---------------------------------------------------------------------------
// Zero only the PAD slots: [row_ptr[n]+cnt[n], row_ptr[n+1]).  ~1.2M pairs.
// Pad entries read as src=0 (row-0 broadcast, L1-hot) with weight 0.
// ---------------------------------------------------------------------------
__global__ void zero_pad(const int* __restrict__ cnt,
                         const int* __restrict__ row_ptr,
                         int2* __restrict__ csr_pair) {
    int t = blockIdx.x * blockDim.x + threadIdx.x;
    int node = t >> 4;
    int lane = t & 15;
    if (node >= N_NODES) return;
    int s = row_ptr[node] + cnt[node];
    int e = row_ptr[node + 1];
    int2 z; z.x = 0; z.y = 0;
    for (int j = s + lane; j < e; j += 16) csr_pair[j] = z;
}

// ---------------------------------------------------------------------------
// Kernel 2: per-edge MLP fused with ATOMIC-FREE CSR scatter.
// ---------------------------------------------------------------------------
__global__ void mlp_scatter(const float* __restrict__ edge_attr,
                            const float* __restrict__ ew,
                            const float* __restrict__ w1,
                            const float* __restrict__ b1,
                            const float* __restrict__ w2,
                            const float* __restrict__ b2,
                            const int*   __restrict__ edge_index,
                            const int*   __restrict__ rank,
                            const int*   __restrict__ row_ptr,
                            int2* __restrict__ csr_pair) {
    __shared__ float w1s[8 * MLP_HID];
    __shared__ float b1s[MLP_HID];
    __shared__ float w2s[MLP_HID];
    int tid = threadIdx.x;
    if (tid < 8 * MLP_HID) w1s[tid] = w1[tid];
    if (tid < MLP_HID) { b1s[tid] = b1[tid]; w2s[tid] = w2[tid]; }
    __syncthreads();

    int e = blockIdx.x * blockDim.x + tid;
    if (e >= NUM_EDGES) return;

    float ef[8];
#pragma unroll
    for (int k = 0; k < 7; ++k) ef[k] = edge_attr[e * 7 + k];
    ef[7] = ew[e];

    float s = b2[0];
#pragma unroll
    for (int j = 0; j < MLP_HID; ++j) {
        float h = b1s[j];
#pragma unroll
        for (int k = 0; k < 8; ++k) h = fmaf(ef[k], w1s[k * MLP_HID + j], h);
        h = fmaxf(h, 0.0f);
        s = fmaf(h, w2s[j], s);
    }
    float w = 1.0f / (1.0f + expf(-s));

    int r = edge_index[e];
    int c = edge_index[NUM_EDGES + e];
    int pos = row_ptr[c] + rank[e];
    int2 pr;
    pr.x = r;
    pr.y = __float_as_int(w);
    csr_pair[pos] = pr;
}

// ---------------------------------------------------------------------------
// deg[node] = segment sum over REAL entries only (cnt bound, skips pads).
// ---------------------------------------------------------------------------
__global__ void deg_dinv_csr(const int* __restrict__ row_ptr,
                             const int* __restrict__ cnt,
                             const int2* __restrict__ csr_pair,
                             float* __restrict__ dinv) {
    int t = blockIdx.x * blockDim.x + threadIdx.x;
    int node = t >> 4;
    int lane = t & 15;
    if (node >= N_NODES) return;
    int s = row_ptr[node], e = s + cnt[node];
    float sum = 0.0f;
    for (int j = s + lane; j < e; j += 16) sum += __int_as_float(csr_pair[j].y);
    sum += __shfl_xor(sum, 8);
    sum += __shfl_xor(sum, 4);
    sum += __shfl_xor(sum, 2);
    sum += __shfl_xor(sum, 1);
    if (lane == 0)
        dinv[node] = (sum > 0.0f) ? rsqrtf(fmaxf(sum, 1e-30f)) : 0.0f;
}

// ---------------------------------------------------------------------------
// pair.w *= dinv[col] * dinv[pair.src]   (real entries only; pads stay 0).
// ---------------------------------------------------------------------------
__global__ void csr_scale(const int* __restrict__ row_ptr,
                          const int* __restrict__ cnt,
                          const float* __restrict__ dinv,
                          int2* __restrict__ csr_pair) {
    int t = blockIdx.x * blockDim.x + threadIdx.x;
    int node = t >> 4;
    int lane = t & 15;
    if (node >= N_NODES) return;
    int s = row_ptr[node], e = s + cnt[node];
    float dc = dinv[node];
    for (int j = s + lane; j < e; j += 16) {
        int2 p = csr_pair[j];
        p.y = __float_as_int(__int_as_float(p.y) * dc * dinv[p.x]);
        csr_pair[j] = p;
    }
}

// ---------------------------------------------------------------------------
// build x0: bf16 only.
// ---------------------------------------------------------------------------
__global__ void init_x(const float* __restrict__ user_w,
                       const float* __restrict__ artist_w,
                       const float* __restrict__ album_w,
                       const float* __restrict__ audio,
                       const int*   __restrict__ artist_ids,
                       const int*   __restrict__ album_ids,
                       __hip_bfloat16* __restrict__ x) {
    int t = blockIdx.x * blockDim.x + threadIdx.x;
    int row = t >> 6;
    int lane = t & 63;
    if (row >= N_NODES) return;

    float v;
    if (row < NUM_USERS) {
        v = user_w[row * EMBED_DIM + lane];
    } else {
        int r = row - NUM_USERS;
        int ar = artist_ids[r];
        int al = album_ids[r];
        v = audio[r * EMBED_DIM + lane]
          + 0.5f * (artist_w[ar * EMBED_DIM + lane] + album_w[al * EMBED_DIM + lane]);
    }
    float ss = v * v;
#pragma unroll
    for (int off = 32; off > 0; off >>= 1) ss += __shfl_xor(ss, off);
    float scale = 1.0f / fmaxf(sqrtf(ss), 1e-12f);
    x[row * EMBED_DIM + lane] = __float2bfloat16(v * scale);
}

// ---------------------------------------------------------------------------
// pull-mode propagation v4: NPW(4) nodes/wave, GUARD-FREE inner loop.
//  - segments padded to multiples of 16 -> no bounds cmp/cndmask at all
//  - contiguous padded segments -> pair pointer advances j += 16 forever,
//    across node boundaries; prefetch depth 1 group (4x8B same-addr loads)
//  - 4 independent uint2 gathers in flight per iteration (each covers 4
//    full 128B node rows across the 4 slot groups)
//  Final prefetch reads <=16 pairs past the padded end: csr_pair is the last
//  workspace region with slack, values never consumed.
// ---------------------------------------------------------------------------
#define BF_LO(u) __uint_as_float((u) << 16)
#define BF_HI(u) __uint_as_float((u) & 0xffff0000u)

__global__ void propagate_mid(const int* __restrict__ row_ptr,
                              const int2* __restrict__ csr_pair,
                              const unsigned short* __restrict__ xin,
                              unsigned short* __restrict__ xout) {
    int wave = (blockIdx.x * blockDim.x + threadIdx.x) >> 6;
    int lane = threadIdx.x & 63;
    int node0 = wave * NPW;
    if (node0 >= N_NODES) return;

    int eg = lane >> 4;          // edge slot 0..3
    int dq = (lane & 15) << 2;   // dim quad start

    int rpv = row_ptr[node0 + (lane <= NPW ? lane : NPW)];
    int rs0 = __shfl(rpv, 0);
    int rs1 = __shfl(rpv, 1);
    int rs2 = __shfl(rpv, 2);
    int rs3 = __shfl(rpv, 3);
    int rs4 = __shfl(rpv, 4);

    int j = rs0 + (eg << 2);
    int2 p0 = csr_pair[j];
    int2 p1 = csr_pair[j + 1];
    int2 p2 = csr_pair[j + 2];
    int2 p3 = csr_pair[j + 3];

#pragma unroll
    for (int k = 0; k < NPW; ++k) {
        int bs = (k == 0) ? rs0 : (k == 1) ? rs1 : (k == 2) ? rs2 : rs3;
        int be = (k == 0) ? rs1 : (k == 1) ? rs2 : (k == 2) ? rs3 : rs4;
        float a0 = 0, a1 = 0, a2 = 0, a3 = 0;

        for (int base = bs; base < be; base += 16) {
            int   s0 = p0.x; float w0 = __int_as_float(p0.y);
            int   s1 = p1.x; float w1 = __int_as_float(p1.y);
            int   s2 = p2.x; float w2 = __int_as_float(p2.y);
            int   s3 = p3.x; float w3 = __int_as_float(p3.y);

            uint2 u0 = *(const uint2*)(xin + ((size_t)s0 << 6) + dq);
            uint2 u1 = *(const uint2*)(xin + ((size_t)s1 << 6) + dq);
            uint2 u2 = *(const uint2*)(xin + ((size_t)s2 << 6) + dq);
            uint2 u3 = *(const uint2*)(xin + ((size_t)s3 << 6) + dq);

            j += 16;                       // contiguous: always next group
            p0 = csr_pair[j];
            p1 = csr_pair[j + 1];
            p2 = csr_pair[j + 2];
            p3 = csr_pair[j + 3];

            a0 = fmaf(w0, BF_LO(u0.x), a0); a1 = fmaf(w0, BF_HI(u0.x), a1);
            a2 = fmaf(w0, BF_LO(u0.y), a2); a3 = fmaf(w0, BF_HI(u0.y), a3);
            a0 = fmaf(w1, BF_LO(u1.x), a0); a1 = fmaf(w1, BF_HI(u1.x), a1);
            a2 = fmaf(w1, BF_LO(u1.y), a2); a3 = fmaf(w1, BF_HI(u1.y), a3);
            a0 = fmaf(w2, BF_LO(u2.x), a0); a1 = fmaf(w2, BF_HI(u2.x), a1);
            a2 = fmaf(w2, BF_LO(u2.y), a2); a3 = fmaf(w2, BF_HI(u2.y), a3);
            a0 = fmaf(w3, BF_LO(u3.x), a0); a1 = fmaf(w3, BF_HI(u3.x), a1);
            a2 = fmaf(w3, BF_LO(u3.y), a2); a3 = fmaf(w3, BF_HI(u3.y), a3);
        }

        a0 += __shfl_xor(a0, 16); a1 += __shfl_xor(a1, 16);
        a2 += __shfl_xor(a2, 16); a3 += __shfl_xor(a3, 16);
        a0 += __shfl_xor(a0, 32); a1 += __shfl_xor(a1, 32);
        a2 += __shfl_xor(a2, 32); a3 += __shfl_xor(a3, 32);

        if (eg == 0) {
            size_t o = ((size_t)(node0 + k) << 6) + dq;
            unsigned int b0 = (unsigned int)__bfloat16_as_ushort(__float2bfloat16(a0));
            unsigned int b1 = (unsigned int)__bfloat16_as_ushort(__float2bfloat16(a1));
            unsigned int b2 = (unsigned int)__bfloat16_as_ushort(__float2bfloat16(a2));
            unsigned int b3 = (unsigned int)__bfloat16_as_ushort(__float2bfloat16(a3));
            uint2 u;
            u.x = b0 | (b1 << 16);
            u.y = b2 | (b3 << 16);
            *(uint2*)(xout + o) = u;
        }
    }
}

// ---------------------------------------------------------------------------
// FINAL layer: gather from x2, then out = l2norm((x0+x1+x2+a)/4), f32.
// ---------------------------------------------------------------------------
__global__ void propagate_final(const int* __restrict__ row_ptr,
                                const int2* __restrict__ csr_pair,
                                const unsigned short* __restrict__ x0,
                                const unsigned short* __restrict__ x1,
                                const unsigned short* __restrict__ x2,
                                float* __restrict__ outp) {
    int wave = (blockIdx.x * blockDim.x + threadIdx.x) >> 6;
    int lane = threadIdx.x & 63;
    int node0 = wave * NPW;
    if (node0 >= N_NODES) return;

    int eg = lane >> 4;
    int dq = (lane & 15) << 2;

    int rpv = row_ptr[node0 + (lane <= NPW ? lane : NPW)];
    int rs0 = __shfl(rpv, 0);
    int rs1 = __shfl(rpv, 1);
    int rs2 = __shfl(rpv, 2);
    int rs3 = __shfl(rpv, 3);
    int rs4 = __shfl(rpv, 4);

    int j = rs0 + (eg << 2);
    int2 p0 = csr_pair[j];
    int2 p1 = csr_pair[j + 1];
    int2 p2 = csr_pair[j + 2];
    int2 p3 = csr_pair[j + 3];

#pragma unroll
    for (int k = 0; k < NPW; ++k) {
        int bs = (k == 0) ? rs0 : (k == 1) ? rs1 : (k == 2) ? rs2 : rs3;
        int be = (k == 0) ? rs1 : (k == 1) ? rs2 : (k == 2) ? rs3 : rs4;
        float a0 = 0, a1 = 0, a2 = 0, a3 = 0;

        for (int base = bs; base < be; base += 16) {
            int   s0 = p0.x; float w0 = __int_as_float(p0.y);
            int   s1 = p1.x; float w1 = __int_as_float(p1.y);
            int   s2 = p2.x; float w2 = __int_as_float(p2.y);
            int   s3 = p3.x; float w3 = __int_as_float(p3.y);

            uint2 u0 = *(const uint2*)(x2 + ((size_t)s0 << 6) + dq);
            uint2 u1 = *(const uint2*)(x2 + ((size_t)s1 << 6) + dq);
            uint2 u2 = *(const uint2*)(x2 + ((size_t)s2 << 6) + dq);
            uint2 u3 = *(const uint2*)(x2 + ((size_t)s3 << 6) + dq);

            j += 16;
            p0 = csr_pair[j];
            p1 = csr_pair[j + 1];
            p2 = csr_pair[j + 2];
            p3 = csr_pair[j + 3];

            a0 = fmaf(w0, BF_LO(u0.x), a0); a1 = fmaf(w0, BF_HI(u0.x), a1);
            a2 = fmaf(w0, BF_LO(u0.y), a2); a3 = fmaf(w0, BF_HI(u0.y), a3);
            a0 = fmaf(w1, BF_LO(u1.x), a0); a1 = fmaf(w1, BF_HI(u1.x), a1);
            a2 = fmaf(w1, BF_LO(u1.y), a2); a3 = fmaf(w1, BF_HI(u1.y), a3);
            a0 = fmaf(w2, BF_LO(u2.x), a0); a1 = fmaf(w2, BF_HI(u2.x), a1);
            a2 = fmaf(w2, BF_LO(u2.y), a2); a3 = fmaf(w2, BF_HI(u2.y), a3);
            a0 = fmaf(w3, BF_LO(u3.x), a0); a1 = fmaf(w3, BF_HI(u3.x), a1);
            a2 = fmaf(w3, BF_LO(u3.y), a2); a3 = fmaf(w3, BF_HI(u3.y), a3);
        }

        a0 += __shfl_xor(a0, 16); a1 += __shfl_xor(a1, 16);
        a2 += __shfl_xor(a2, 16); a3 += __shfl_xor(a3, 16);
        a0 += __shfl_xor(a0, 32); a1 += __shfl_xor(a1, 32);
        a2 += __shfl_xor(a2, 32); a3 += __shfl_xor(a3, 32);

        if (eg == 0) {
            size_t o = ((size_t)(node0 + k) << 6) + dq;
            uint2 u0 = *(const uint2*)(x0 + o);
            uint2 u1 = *(const uint2*)(x1 + o);
            uint2 u2 = *(const uint2*)(x2 + o);

            float v0 = (BF_LO(u0.x) + BF_LO(u1.x) + BF_LO(u2.x) + a0) * 0.25f;
            float v1 = (BF_HI(u0.x) + BF_HI(u1.x) + BF_HI(u2.x) + a1) * 0.25f;
            float v2 = (BF_LO(u0.y) + BF_LO(u1.y) + BF_LO(u2.y) + a2) * 0.25f;
            float v3 = (BF_HI(u0.y) + BF_HI(u1.y) + BF_HI(u2.y) + a3) * 0.25f;

            float ss = v0 * v0 + v1 * v1 + v2 * v2 + v3 * v3;
            ss += __shfl_xor(ss, 1);
            ss += __shfl_xor(ss, 2);
            ss += __shfl_xor(ss, 4);
            ss += __shfl_xor(ss, 8);
            float scale = 1.0f / fmaxf(sqrtf(ss), 1e-12f);

            float4 r = { v0 * scale, v1 * scale, v2 * scale, v3 * scale };
            *(float4*)(outp + o) = r;
        }
    }
    if (blockIdx.x == 0 && threadIdx.x == 0)
        outp[(size_t)N_NODES * EMBED_DIM] = 0.0f;  // align_loss
}

#undef BF_LO
#undef BF_HI

// ---------------------------------------------------------------------------
extern "C" void kernel_launch(void* const* d_in, const int* in_sizes, int n_in,
                              void* d_out, int out_size, void* d_ws, size_t ws_size,
                              hipStream_t stream) {
    const float* user_w     = (const float*)d_in[0];
    const float* artist_w   = (const float*)d_in[1];
    const float* album_w    = (const float*)d_in[2];
    const float* audio      = (const float*)d_in[3];
    const float* edge_attr  = (const float*)d_in[4];
    const float* ew         = (const float*)d_in[5];
    const float* w1         = (const float*)d_in[6];
    const float* b1         = (const float*)d_in[7];
    const float* w2         = (const float*)d_in[8];
    const float* b2         = (const float*)d_in[9];
    const int*   edge_index = (const int*)d_in[10];
    const int*   artist_ids = (const int*)d_in[11];
    const int*   album_ids  = (const int*)d_in[12];
    float* out = (float*)d_out;

    float* ws = (float*)d_ws;
    // Persistent regions (offsets in float units):
    unsigned short* x0 = (unsigned short*)ws;                // 9.6M bf16
    unsigned short* x1 = (unsigned short*)(ws + 4800000);    // 9.6M bf16
    unsigned short* x2 = (unsigned short*)(ws + 9600000);    // 9.6M bf16
    int*  row_ptr  = (int*)(ws + 14400000);                  // 150001 ints
    int2* csr_pair = (int2*)(ws + 14560000);                 // padded CSR, LAST
                                                             // region (~2.45M
                                                             // pairs + slack)
    // Transients aliased into x0 region (all dead before init_x writes x0):
    int*   cnt     = (int*)ws;                               // 150k ints
    int*   rank    = (int*)(ws + 150000);                    // 1.25M ints
    int*   part    = (int*)(ws + 1400000);                   // 147 ints
    int*   baseoff = (int*)(ws + 1401000);                   // 147 ints
    float* dinv    = ws + 1402000;                           // 150k floats

    const int B = 256;
    const int egrid   = (NUM_EDGES + B - 1) / B;
    const int ngrid   = (N_NODES * EMBED_DIM) / B;           // wave-per-node grids
    const int ngrid16 = (N_NODES * 16) / B;                  // 16-lane-per-node grids
    const int pgrid   = (N_NODES / NPW * 64) / B;            // NPW-nodes-per-wave grids

    hipMemsetAsync(cnt, 0, N_NODES * sizeof(int), stream);

    hist_rank<<<egrid, B, 0, stream>>>(edge_index, cnt, rank);

    scan_partial<<<SCAN_NB, SCAN_B, 0, stream>>>(cnt, part);
    scan_offsets<<<1, 256, 0, stream>>>(part, baseoff);
    scan_apply<<<SCAN_NB, SCAN_B, 0, stream>>>(cnt, baseoff, row_ptr);

    zero_pad<<<ngrid16, B, 0, stream>>>(cnt, row_ptr, csr_pair);

    mlp_scatter<<<egrid, B, 0, stream>>>(
        edge_attr, ew, w1, b1, w2, b2, edge_index, rank, row_ptr, csr_pair);

    deg_dinv_csr<<<ngrid16, B, 0, stream>>>(row_ptr, cnt, csr_pair, dinv);
    csr_scale<<<ngrid16, B, 0, stream>>>(row_ptr, cnt, dinv, csr_pair);

    init_x<<<ngrid, B, 0, stream>>>(
        user_w, artist_w, album_w, audio, artist_ids, album_ids,
        (__hip_bfloat16*)x0);

    propagate_mid<<<pgrid, B, 0, stream>>>(row_ptr, csr_pair, x0, x1);
    propagate_mid<<<pgrid, B, 0, stream>>>(row_ptr, csr_pair, x1, x2);
    propagate_final<<<pgrid, B, 0, stream>>>(row_ptr, csr_pair, x0, x1, x2, out);
}

// Round 4
// 401.177 us; speedup vs baseline: 1.0495x; 1.0495x over previous
//
#include <hip/hip_runtime.h>
#include <hip/hip_bf16.h>
#include <math.h>

#define NUM_USERS  100000
#define NUM_ITEMS  50000
#define N_NODES    150000
#define EMBED_DIM  64
#define NUM_EDGES  1250000
#define MLP_HID    32
#define SCAN_B     1024
#define SCAN_NB    ((N_NODES + SCAN_B - 1) / SCAN_B)   // 147
#define NPW        4                                   // nodes per wave
#define PAD(x)     (((x) + 7) & ~7)                    // segment pad to 8

// ---------------------------------------------------------------------------
// hist + per-edge MLP fused: rank via atomicAdd (rank IS the CSR slot),
// w via 2-layer MLP, epair[e] = {src_row, w} written in e-order (streaming).
// MLP VALU (~300 instr) hides under the atomic latency.
// ---------------------------------------------------------------------------
__global__ void hist_mlp(const float* __restrict__ edge_attr,
                         const float* __restrict__ ew,
                         const float* __restrict__ w1,
                         const float* __restrict__ b1,
                         const float* __restrict__ w2,
                         const float* __restrict__ b2,
                         const int*   __restrict__ edge_index,
                         int*  __restrict__ cnt,
                         int*  __restrict__ rank,
                         int2* __restrict__ epair) {
    __shared__ float w1s[8 * MLP_HID];
    __shared__ float b1s[MLP_HID];
    __shared__ float w2s[MLP_HID];
    int tid = threadIdx.x;
    if (tid < 8 * MLP_HID) w1s[tid] = w1[tid];
    if (tid < MLP_HID) { b1s[tid] = b1[tid]; w2s[tid] = w2[tid]; }
    __syncthreads();

    int e = blockIdx.x * blockDim.x + tid;
    if (e >= NUM_EDGES) return;

    int c = edge_index[NUM_EDGES + e];
    rank[e] = atomicAdd(&cnt[c], 1);

    float ef[8];
#pragma unroll
    for (int k = 0; k < 7; ++k) ef[k] = edge_attr[e * 7 + k];
    ef[7] = ew[e];

    float s = b2[0];
#pragma unroll
    for (int j = 0; j < MLP_HID; ++j) {
        float h = b1s[j];
#pragma unroll
        for (int k = 0; k < 8; ++k) h = fmaf(ef[k], w1s[k * MLP_HID + j], h);
        h = fmaxf(h, 0.0f);
        s = fmaf(h, w2s[j], s);
    }
    float w = 1.0f / (1.0f + expf(-s));

    int2 pr;
    pr.x = edge_index[e];          // src row
    pr.y = __float_as_int(w);
    epair[e] = pr;                 // streaming, coalesced
}

// ---------------------------------------------------------------------------
// Device-wide exclusive scan of PAD8(cnt) -> row_ptr, 3 phases.
// ---------------------------------------------------------------------------
__global__ void scan_partial(const int* __restrict__ cnt,
                             int* __restrict__ part) {
    __shared__ int s[SCAN_B];
    int tid = threadIdx.x;
    int i = blockIdx.x * SCAN_B + tid;
    s[tid] = (i < N_NODES) ? PAD(cnt[i]) : 0;
    __syncthreads();
#pragma unroll
    for (int off = SCAN_B / 2; off > 0; off >>= 1) {
        if (tid < off) s[tid] += s[tid + off];
        __syncthreads();
    }
    if (tid == 0) part[blockIdx.x] = s[0];
}

__global__ void scan_offsets(const int* __restrict__ part,
                             int* __restrict__ base_off) {
    __shared__ int s[256];
    int tid = threadIdx.x;
    int v = (tid < SCAN_NB) ? part[tid] : 0;
    s[tid] = v;
    __syncthreads();
#pragma unroll
    for (int off = 1; off < 256; off <<= 1) {
        int t = (tid >= off) ? s[tid - off] : 0;
        __syncthreads();
        s[tid] += t;
        __syncthreads();
    }
    if (tid < SCAN_NB) base_off[tid] = s[tid] - v;   // exclusive
}

__global__ void scan_apply(const int* __restrict__ cnt,
                           const int* __restrict__ base_off,
                           int* __restrict__ row_ptr) {
    __shared__ int s[SCAN_B];
    int tid = threadIdx.x;
    int i = blockIdx.x * SCAN_B + tid;
    int v = (i < N_NODES) ? PAD(cnt[i]) : 0;
    s[tid] = v;
    __syncthreads();
    for (int off = 1; off < SCAN_B; off <<= 1) {
        int t = (tid >= off) ? s[tid - off] : 0;
        __syncthreads();
        s[tid] += t;
        __syncthreads();
    }
    if (i < N_NODES) row_ptr[i] = s[tid] - v + base_off[blockIdx.x];
    if (i == N_NODES - 1) row_ptr[N_NODES] = s[tid] + base_off[blockIdx.x];
}

// ---------------------------------------------------------------------------
// perm[row_ptr[c] + rank[e]] = e    (4B random scatter — the only one left)
// ---------------------------------------------------------------------------
__global__ void scatter_perm(const int* __restrict__ edge_index,
                             const int* __restrict__ rank,
                             const int* __restrict__ row_ptr,
                             int* __restrict__ perm) {
    int e = blockIdx.x * blockDim.x + threadIdx.x;
    if (e >= NUM_EDGES) return;
    int c = edge_index[NUM_EDGES + e];
    perm[row_ptr[c] + rank[e]] = e;
}

// ---------------------------------------------------------------------------
// Build padded CSR in GATHER mode (streaming fully-dirty writes), zero pads
// inline, and fuse deg -> dinv (node-major, 16 lanes/node).
// Random reads: epair[perm[j]] — one 8B gather into a 10MB L3/L2-hot array.
// ---------------------------------------------------------------------------
__global__ void pair_build(const int* __restrict__ row_ptr,
                           const int* __restrict__ cnt,
                           const int* __restrict__ perm,
                           const int2* __restrict__ epair,
                           int2* __restrict__ csr_pair,
                           float* __restrict__ dinv) {
    int t = blockIdx.x * blockDim.x + threadIdx.x;
    int node = t >> 4;
    int lane = t & 15;
    if (node >= N_NODES) return;
    int s = row_ptr[node];
    int e = row_ptr[node + 1];
    int re = s + cnt[node];
    float sum = 0.0f;
    for (int j = s + lane; j < e; j += 16) {
        int2 pr;
        if (j < re) {
            int eid = perm[j];
            pr = epair[eid];
            sum += __int_as_float(pr.y);
        } else {
            pr.x = 0; pr.y = 0;
        }
        csr_pair[j] = pr;
    }
    sum += __shfl_xor(sum, 8);
    sum += __shfl_xor(sum, 4);
    sum += __shfl_xor(sum, 2);
    sum += __shfl_xor(sum, 1);
    if (lane == 0)
        dinv[node] = (sum > 0.0f) ? rsqrtf(fmaxf(sum, 1e-30f)) : 0.0f;
}

// ---------------------------------------------------------------------------
// build x0: bf16 only.
// ---------------------------------------------------------------------------
__global__ void init_x(const float* __restrict__ user_w,
                       const float* __restrict__ artist_w,
                       const float* __restrict__ album_w,
                       const float* __restrict__ audio,
                       const int*   __restrict__ artist_ids,
                       const int*   __restrict__ album_ids,
                       __hip_bfloat16* __restrict__ x) {
    int t = blockIdx.x * blockDim.x + threadIdx.x;
    int row = t >> 6;
    int lane = t & 63;
    if (row >= N_NODES) return;

    float v;
    if (row < NUM_USERS) {
        v = user_w[row * EMBED_DIM + lane];
    } else {
        int r = row - NUM_USERS;
        int ar = artist_ids[r];
        int al = album_ids[r];
        v = audio[r * EMBED_DIM + lane]
          + 0.5f * (artist_w[ar * EMBED_DIM + lane] + album_w[al * EMBED_DIM + lane]);
    }
    float ss = v * v;
#pragma unroll
    for (int off = 32; off > 0; off >>= 1) ss += __shfl_xor(ss, off);
    float scale = 1.0f / fmaxf(sqrtf(ss), 1e-12f);
    x[row * EMBED_DIM + lane] = __float2bfloat16(v * scale);
}

// ---------------------------------------------------------------------------
// pull-mode propagation v5: NPW(4) nodes/wave, 8-edge granule, pad-8 CSR.
//  - each 16-lane group owns 2 edges/iter -> 8 independent x-row gathers in
//    flight per wave (2x round 3), plus 2 dinv gathers (600KB, L2-hot)
//  - normalization applied on the fly: w*dinv[src] per edge, * dinv[node]
//    once per node after reduction (csr_scale pass ELIMINATED)
//  - guard-free inner loop; pair pointer advances j+=8 across node bounds
//  Prefetch overruns <=12 pairs past padded end: csr_pair region has slack.
// ---------------------------------------------------------------------------
#define BF_LO(u) __uint_as_float((u) << 16)
#define BF_HI(u) __uint_as_float((u) & 0xffff0000u)

__global__ void propagate_mid(const int* __restrict__ row_ptr,
                              const int2* __restrict__ csr_pair,
                              const float* __restrict__ dinv,
                              const unsigned short* __restrict__ xin,
                              unsigned short* __restrict__ xout) {
    int wave = (blockIdx.x * blockDim.x + threadIdx.x) >> 6;
    int lane = threadIdx.x & 63;
    int node0 = wave * NPW;
    if (node0 >= N_NODES) return;

    int eg = lane >> 4;          // edge slot group 0..3
    int dq = (lane & 15) << 2;   // dim quad start

    int rpv = row_ptr[node0 + (lane <= NPW ? lane : NPW)];
    int rs0 = __shfl(rpv, 0);
    int rs1 = __shfl(rpv, 1);
    int rs2 = __shfl(rpv, 2);
    int rs3 = __shfl(rpv, 3);
    int rs4 = __shfl(rpv, 4);

    int j = rs0 + eg;
    int2 pa = csr_pair[j];       // edge base+eg
    int2 pb = csr_pair[j + 4];   // edge base+4+eg

#pragma unroll
    for (int k = 0; k < NPW; ++k) {
        int bs = (k == 0) ? rs0 : (k == 1) ? rs1 : (k == 2) ? rs2 : rs3;
        int be = (k == 0) ? rs1 : (k == 1) ? rs2 : (k == 2) ? rs3 : rs4;
        float a0 = 0, a1 = 0, a2 = 0, a3 = 0;

        for (int base = bs; base < be; base += 8) {
            int   sa = pa.x; float wa = __int_as_float(pa.y);
            int   sb = pb.x; float wb = __int_as_float(pb.y);
            float da = dinv[sa];
            float db = dinv[sb];
            uint2 ua = *(const uint2*)(xin + ((size_t)sa << 6) + dq);
            uint2 ub = *(const uint2*)(xin + ((size_t)sb << 6) + dq);

            j += 8;                         // contiguous across nodes
            pa = csr_pair[j];
            pb = csr_pair[j + 4];

            float fa = wa * da;
            float fb = wb * db;
            a0 = fmaf(fa, BF_LO(ua.x), a0); a1 = fmaf(fa, BF_HI(ua.x), a1);
            a2 = fmaf(fa, BF_LO(ua.y), a2); a3 = fmaf(fa, BF_HI(ua.y), a3);
            a0 = fmaf(fb, BF_LO(ub.x), a0); a1 = fmaf(fb, BF_HI(ub.x), a1);
            a2 = fmaf(fb, BF_LO(ub.y), a2); a3 = fmaf(fb, BF_HI(ub.y), a3);
        }

        a0 += __shfl_xor(a0, 16); a1 += __shfl_xor(a1, 16);
        a2 += __shfl_xor(a2, 16); a3 += __shfl_xor(a3, 16);
        a0 += __shfl_xor(a0, 32); a1 += __shfl_xor(a1, 32);
        a2 += __shfl_xor(a2, 32); a3 += __shfl_xor(a3, 32);

        if (eg == 0) {
            float dc = dinv[node0 + k];     // node-uniform factor, once
            size_t o = ((size_t)(node0 + k) << 6) + dq;
            unsigned int b0 = (unsigned int)__bfloat16_as_ushort(__float2bfloat16(a0 * dc));
            unsigned int b1 = (unsigned int)__bfloat16_as_ushort(__float2bfloat16(a1 * dc));
            unsigned int b2 = (unsigned int)__bfloat16_as_ushort(__float2bfloat16(a2 * dc));
            unsigned int b3 = (unsigned int)__bfloat16_as_ushort(__float2bfloat16(a3 * dc));
            uint2 u;
            u.x = b0 | (b1 << 16);
            u.y = b2 | (b3 << 16);
            *(uint2*)(xout + o) = u;
        }
    }
}

// ---------------------------------------------------------------------------
// FINAL layer: gather from x2, then out = l2norm((x0+x1+x2+a*dc)/4), f32.
// ---------------------------------------------------------------------------
__global__ void propagate_final(const int* __restrict__ row_ptr,
                                const int2* __restrict__ csr_pair,
                                const float* __restrict__ dinv,
                                const unsigned short* __restrict__ x0,
                                const unsigned short* __restrict__ x1,
                                const unsigned short* __restrict__ x2,
                                float* __restrict__ outp) {
    int wave = (blockIdx.x * blockDim.x + threadIdx.x) >> 6;
    int lane = threadIdx.x & 63;
    int node0 = wave * NPW;
    if (node0 >= N_NODES) return;

    int eg = lane >> 4;
    int dq = (lane & 15) << 2;

    int rpv = row_ptr[node0 + (lane <= NPW ? lane : NPW)];
    int rs0 = __shfl(rpv, 0);
    int rs1 = __shfl(rpv, 1);
    int rs2 = __shfl(rpv, 2);
    int rs3 = __shfl(rpv, 3);
    int rs4 = __shfl(rpv, 4);

    int j = rs0 + eg;
    int2 pa = csr_pair[j];
    int2 pb = csr_pair[j + 4];

#pragma unroll
    for (int k = 0; k < NPW; ++k) {
        int bs = (k == 0) ? rs0 : (k == 1) ? rs1 : (k == 2) ? rs2 : rs3;
        int be = (k == 0) ? rs1 : (k == 1) ? rs2 : (k == 2) ? rs3 : rs4;
        float a0 = 0, a1 = 0, a2 = 0, a3 = 0;

        for (int base = bs; base < be; base += 8) {
            int   sa = pa.x; float wa = __int_as_float(pa.y);
            int   sb = pb.x; float wb = __int_as_float(pb.y);
            float da = dinv[sa];
            float db = dinv[sb];
            uint2 ua = *(const uint2*)(x2 + ((size_t)sa << 6) + dq);
            uint2 ub = *(const uint2*)(x2 + ((size_t)sb << 6) + dq);

            j += 8;
            pa = csr_pair[j];
            pb = csr_pair[j + 4];

            float fa = wa * da;
            float fb = wb * db;
            a0 = fmaf(fa, BF_LO(ua.x), a0); a1 = fmaf(fa, BF_HI(ua.x), a1);
            a2 = fmaf(fa, BF_LO(ua.y), a2); a3 = fmaf(fa, BF_HI(ua.y), a3);
            a0 = fmaf(fb, BF_LO(ub.x), a0); a1 = fmaf(fb, BF_HI(ub.x), a1);
            a2 = fmaf(fb, BF_LO(ub.y), a2); a3 = fmaf(fb, BF_HI(ub.y), a3);
        }

        a0 += __shfl_xor(a0, 16); a1 += __shfl_xor(a1, 16);
        a2 += __shfl_xor(a2, 16); a3 += __shfl_xor(a3, 16);
        a0 += __shfl_xor(a0, 32); a1 += __shfl_xor(a1, 32);
        a2 += __shfl_xor(a2, 32); a3 += __shfl_xor(a3, 32);

        if (eg == 0) {
            float dc = dinv[node0 + k];
            size_t o = ((size_t)(node0 + k) << 6) + dq;
            uint2 u0 = *(const uint2*)(x0 + o);
            uint2 u1 = *(const uint2*)(x1 + o);
            uint2 u2 = *(const uint2*)(x2 + o);

            float v0 = (BF_LO(u0.x) + BF_LO(u1.x) + BF_LO(u2.x) + a0 * dc) * 0.25f;
            float v1 = (BF_HI(u0.x) + BF_HI(u1.x) + BF_HI(u2.x) + a1 * dc) * 0.25f;
            float v2 = (BF_LO(u0.y) + BF_LO(u1.y) + BF_LO(u2.y) + a2 * dc) * 0.25f;
            float v3 = (BF_HI(u0.y) + BF_HI(u1.y) + BF_HI(u2.y) + a3 * dc) * 0.25f;

            float ss = v0 * v0 + v1 * v1 + v2 * v2 + v3 * v3;
            ss += __shfl_xor(ss, 1);
            ss += __shfl_xor(ss, 2);
            ss += __shfl_xor(ss, 4);
            ss += __shfl_xor(ss, 8);
            float scale = 1.0f / fmaxf(sqrtf(ss), 1e-12f);

            float4 r = { v0 * scale, v1 * scale, v2 * scale, v3 * scale };
            *(float4*)(outp + o) = r;
        }
    }
    if (blockIdx.x == 0 && threadIdx.x == 0)
        outp[(size_t)N_NODES * EMBED_DIM] = 0.0f;  // align_loss
}

#undef BF_LO
#undef BF_HI

// ---------------------------------------------------------------------------
extern "C" void kernel_launch(void* const* d_in, const int* in_sizes, int n_in,
                              void* d_out, int out_size, void* d_ws, size_t ws_size,
                              hipStream_t stream) {
    const float* user_w     = (const float*)d_in[0];
    const float* artist_w   = (const float*)d_in[1];
    const float* album_w    = (const float*)d_in[2];
    const float* audio      = (const float*)d_in[3];
    const float* edge_attr  = (const float*)d_in[4];
    const float* ew         = (const float*)d_in[5];
    const float* w1         = (const float*)d_in[6];
    const float* b1         = (const float*)d_in[7];
    const float* w2         = (const float*)d_in[8];
    const float* b2         = (const float*)d_in[9];
    const int*   edge_index = (const int*)d_in[10];
    const int*   artist_ids = (const int*)d_in[11];
    const int*   album_ids  = (const int*)d_in[12];
    float* out = (float*)d_out;

    float* ws = (float*)d_ws;
    // Persistent regions (float-unit offsets):
    unsigned short* x0 = (unsigned short*)ws;                // 9.6M bf16 (0..4.8M)
    unsigned short* x1 = (unsigned short*)(ws + 4800000);    // 9.6M bf16
    unsigned short* x2 = (unsigned short*)(ws + 9600000);    // 9.6M bf16
    float* dinv    = ws + 14400000;                          // 150k floats
    int*  row_ptr  = (int*)(ws + 14560000);                  // 150001 ints
    int2* csr_pair = (int2*)(ws + 14720000);                 // padded-8 CSR
                                                             // (~1.82M pairs,
                                                             // cap 2.3M + slack)
    // Transients aliased into x0/x1 region (all dead before init_x / props):
    int*   cnt     = (int*)ws;                               // 150k ints
    int*   rank    = (int*)(ws + 150000);                    // 1.25M ints
    int*   part    = (int*)(ws + 1400000);                   // 147 ints
    int*   baseoff = (int*)(ws + 1401000);                   // 147 ints
    int2*  epair   = (int2*)(ws + 1500000);                  // 1.25M pairs (2.5M fl)
    int*   perm    = (int*)(ws + 4800000);                   // <=2.3M ints (in x1)

    const int B = 256;
    const int egrid   = (NUM_EDGES + B - 1) / B;
    const int ngrid   = (N_NODES * EMBED_DIM) / B;           // wave-per-node grids
    const int ngrid16 = (N_NODES * 16) / B;                  // 16-lane-per-node grids
    const int pgrid   = (N_NODES / NPW * 64) / B;            // NPW-nodes-per-wave

    hipMemsetAsync(cnt, 0, N_NODES * sizeof(int), stream);

    hist_mlp<<<egrid, B, 0, stream>>>(
        edge_attr, ew, w1, b1, w2, b2, edge_index, cnt, rank, epair);

    scan_partial<<<SCAN_NB, SCAN_B, 0, stream>>>(cnt, part);
    scan_offsets<<<1, 256, 0, stream>>>(part, baseoff);
    scan_apply<<<SCAN_NB, SCAN_B, 0, stream>>>(cnt, baseoff, row_ptr);

    scatter_perm<<<egrid, B, 0, stream>>>(edge_index, rank, row_ptr, perm);

    pair_build<<<ngrid16, B, 0, stream>>>(
        row_ptr, cnt, perm, epair, csr_pair, dinv);

    init_x<<<ngrid, B, 0, stream>>>(
        user_w, artist_w, album_w, audio, artist_ids, album_ids,
        (__hip_bfloat16*)x0);

    propagate_mid<<<pgrid, B, 0, stream>>>(row_ptr, csr_pair, dinv, x0, x1);
    propagate_mid<<<pgrid, B, 0, stream>>>(row_ptr, csr_pair, dinv, x1, x2);
    propagate_final<<<pgrid, B, 0, stream>>>(row_ptr, csr_pair, dinv, x0, x1, x2, out);
}